// Round 8
// baseline (206.294 us; speedup 1.0000x reference)
//
#include <hip/hip_runtime.h>
#include <hip/hip_bf16.h>

#define TQ_  100
#define TS_  100
#define E_   512
#define D_   512
#define K_   1024
#define NBQ  800            // B*TQ blocks, one (b,q) each
#define MR   112            // padded m rows (7 MFMA m-tiles; rows 100-111 garbage)
#define NTHREADS 512        // 8 waves, wave w owns n-slab [w*64, w*64+64)

typedef __attribute__((ext_vector_type(4))) float f32x4;
typedef __attribute__((ext_vector_type(8))) short bf16x8;

__device__ __forceinline__ short f2bf(float f) {
  __hip_bfloat16 h = __float2bfloat16(f);
  return *reinterpret_cast<short*>(&h);
}

__device__ __forceinline__ float fast_tanh(float x) {
  float e = __expf(2.0f * x);
  return 1.0f - 2.0f / (e + 1.0f);
}

// ---- prep: W1 [k=1024][n=512] f32 -> Bpk, streaming-fragment tiles.
// Tile (nt, kc) = 16 n x 32 k, 1 KB: lane l = lg*16+lr holds 16B =
// B[n = nt*16 + lr][k = kc*32 + lg*8 .. +8].  A wave loads one tile with a
// single fully-coalesced dwordx4 at (tile*1024 + lane*16) and the regs are
// directly the verified MFMA B-fragment (lr -> n, lg -> k-octet).
__global__ void prep_w1(const float* __restrict__ W1, short* __restrict__ Bpk) {
  int idx = blockIdx.x * 256 + threadIdx.x;   // over K_*D_
  int k = idx >> 9;            // 0..1023
  int n = idx & (D_ - 1);      // 0..511
  int kc = k >> 5, lg = (k >> 3) & 3, w = k & 7;
  int nt = n >> 4, lr = n & 15;
  Bpk[(((size_t)(nt * 32 + kc)) << 9) + (size_t)((lg * 16 + lr) << 3) + w] = f2bf(W1[idx]);
}

// ---- fused: scores GEMM + mask + softmax + weighted sum, one block per (b,q) ----
__launch_bounds__(NTHREADS, 2)
__global__ void fused_kernel(const float* __restrict__ src,
                             const float* __restrict__ tgt,
                             const float* __restrict__ mask,
                             const short* __restrict__ Bpk,
                             const float* __restrict__ b1,
                             const float* __restrict__ w2,
                             float* __restrict__ out) {
  __shared__ __align__(16) char As[MR * 1024];      // src half bf16, 112 KB, swizzled
  __shared__ __align__(16) char At[2][MR * 128];    // tgt chunk dbuf, 28 KB
  __shared__ float s_sc[MR];                         // score accumulators
  __shared__ float s_e[TS_];                         // softmax scratch

  const int tid  = threadIdx.x;
  const int wave = tid >> 6;
  const int lane = tid & 63;
  const int lr   = lane & 15;
  const int lg   = lane >> 4;
  const int bq   = blockIdx.x;
  const int nt0  = wave * 4;          // 4 n-tiles = 64 cols per wave

  f32x4 acc[7][4];
  #pragma unroll
  for (int i = 0; i < 7; i++)
    #pragma unroll
    for (int j = 0; j < 4; j++)
      acc[i][j] = (f32x4){0.f, 0.f, 0.f, 0.f};

  // staging map: thread -> (row srow, 16 consecutive floats at ssub*16)
  const int srow = tid >> 2;          // 0..127, stage only <100
  const int ssub = tid & 3;
  const bool stg = (srow < TS_);
  const int ssw  = (srow & 7) << 4;
  const float* srcg = src + ((size_t)bq * TS_) * E_;
  const float* tgtg = tgt + ((size_t)bq * TS_) * E_;

  if (tid < MR) s_sc[tid] = 0.0f;

  #define LOADQ(P, KF)                                                         \
    { const float* p_ = (P) + (size_t)srow * E_ + (KF);                        \
      q0 = *(const f32x4*)(p_);      q1 = *(const f32x4*)(p_ + 4);             \
      q2 = *(const f32x4*)(p_ + 8);  q3 = *(const f32x4*)(p_ + 12); }

  // write 32 bytes (16 bf16) as two XOR-swizzled 16B pieces
  #define WRITEQ(BASE, RSTR, BOFF)                                             \
    { bf16x8 w0, w1;                                                           \
      w0[0]=f2bf(q0[0]); w0[1]=f2bf(q0[1]); w0[2]=f2bf(q0[2]); w0[3]=f2bf(q0[3]); \
      w0[4]=f2bf(q1[0]); w0[5]=f2bf(q1[1]); w0[6]=f2bf(q1[2]); w0[7]=f2bf(q1[3]); \
      w1[0]=f2bf(q2[0]); w1[1]=f2bf(q2[1]); w1[2]=f2bf(q2[2]); w1[3]=f2bf(q2[3]); \
      w1[4]=f2bf(q3[0]); w1[5]=f2bf(q3[1]); w1[6]=f2bf(q3[2]); w1[7]=f2bf(q3[3]); \
      *(bf16x8*)((BASE) + (size_t)srow * (RSTR) + (((BOFF)      ) ^ ssw)) = w0; \
      *(bf16x8*)((BASE) + (size_t)srow * (RSTR) + (((BOFF) + 16) ^ ssw)) = w1; }

  // one 32-k slice: B frags straight from L2 (coalesced), A frags from LDS
  #define COMPUTE_KK(ABASE, RSTR, BYOFF, KC)                                   \
    { bf16x8 b[4], a[7];                                                       \
      _Pragma("unroll")                                                        \
      for (int j = 0; j < 4; j++)                                              \
        b[j] = *(const bf16x8*)(Bpk + (((size_t)((nt0 + j) * 32 + (KC))) << 9) \
                                + (size_t)lane * 8);                           \
      _Pragma("unroll")                                                        \
      for (int mi = 0; mi < 7; mi++) {                                         \
        int row = mi * 16 + lr;                                                \
        a[mi] = *(const bf16x8*)((ABASE) + (size_t)row * (RSTR) +              \
                    (((BYOFF) + lg * 16) ^ ((row & 7) << 4)));                 \
      }                                                                        \
      __builtin_amdgcn_s_setprio(1);                                           \
      _Pragma("unroll")                                                        \
      for (int mi = 0; mi < 7; mi++)                                           \
        _Pragma("unroll")                                                      \
        for (int ni = 0; ni < 4; ni++)                                         \
          acc[mi][ni] = __builtin_amdgcn_mfma_f32_16x16x32_bf16(               \
              a[mi], b[ni], acc[mi][ni], 0, 0, 0);                             \
      __builtin_amdgcn_s_setprio(0); }

  // ---- prologue: stage tgt chunk 0 into At[0] ----
  {
    f32x4 q0, q1, q2, q3;
    if (stg) { LOADQ(tgtg, ssub * 16); WRITEQ(At[0], 128, ssub * 32); }
  }
  __syncthreads();

  // ---- phase 2: tgt chunks (k = 512 + c*64), 1 barrier each; src staged under ----
  for (int c = 0; c < 8; ++c) {
    f32x4 q0, q1, q2, q3, p0, p1, p2, p3;
    if (stg) {
      if (c < 7) { LOADQ(tgtg, (c + 1) * 64 + ssub * 16); }
      { const float* p_ = srcg + (size_t)srow * E_ + c * 64 + ssub * 16;
        p0 = *(const f32x4*)(p_);      p1 = *(const f32x4*)(p_ + 4);
        p2 = *(const f32x4*)(p_ + 8);  p3 = *(const f32x4*)(p_ + 12); }
    }
    COMPUTE_KK(At[c & 1], 128,  0, 16 + 2 * c);
    COMPUTE_KK(At[c & 1], 128, 64, 17 + 2 * c);
    if (stg) {
      if (c < 7) WRITEQ(At[(c + 1) & 1], 128, ssub * 32);
      q0 = p0; q1 = p1; q2 = p2; q3 = p3;
      WRITEQ(As, 1024, c * 128 + ssub * 32);
    }
    __syncthreads();
  }

  // ---- phase 3: src chunks (k = c*64), NO barriers: A read-only in LDS ----
  for (int c = 0; c < 8; ++c) {
    COMPUTE_KK(As, 1024, c * 128,      2 * c);
    COMPUTE_KK(As, 1024, c * 128 + 64, 2 * c + 1);
  }

  // ---- epilogue: partial scores -> s_sc (atomic, verified R1 pattern) ----
  float b1v[4], w2v[4];
  #pragma unroll
  for (int ni = 0; ni < 4; ni++) {
    int n = wave * 64 + ni * 16 + lr;
    b1v[ni] = b1[n];
    w2v[ni] = w2[n];
  }
  #pragma unroll
  for (int mi = 0; mi < 7; mi++) {
    #pragma unroll
    for (int r = 0; r < 4; r++) {
      float p = 0.0f;
      #pragma unroll
      for (int ni = 0; ni < 4; ni++)
        p += fast_tanh(acc[mi][ni][r] + b1v[ni]) * w2v[ni];
      p += __shfl_xor(p, 1);
      p += __shfl_xor(p, 2);
      p += __shfl_xor(p, 4);
      p += __shfl_xor(p, 8);
      if (lr == 0) atomicAdd(&s_sc[mi * 16 + lg * 4 + r], p);
    }
  }
  __syncthreads();

  // ---- softmax over s (in-block) ----
  if (tid < TS_) s_e[tid] = s_sc[tid] * mask[(size_t)bq * TS_ + tid];
  __syncthreads();
  float mx = -3.0e38f;
  for (int s = 0; s < TS_; s++) mx = fmaxf(mx, s_e[s]);   // LDS broadcast
  __syncthreads();
  if (tid < TS_) s_sc[tid] = __expf(s_e[tid] - mx);
  __syncthreads();
  float sum = 0.0f;
  for (int s = 0; s < TS_; s++) sum += s_sc[s];
  const float inv = 1.0f / sum;

  float* out_attn = out;                            // [800][512]
  float* out_w    = out + (size_t)NBQ * E_;         // [800][100]
  if (tid < TS_) out_w[(size_t)bq * TS_ + tid] = s_sc[tid] * inv;

  // ---- weighted sum: thread t owns col e=t; src f32 from L2 (accurate) ----
  const float* sp = srcg + tid;
  float a2 = 0.0f;
  #pragma unroll 4
  for (int s = 0; s < TS_; s++) a2 = fmaf(s_sc[s], sp[(size_t)s * E_], a2);
  out_attn[(size_t)bq * E_ + tid] = a2 * inv;
}

extern "C" void kernel_launch(void* const* d_in, const int* in_sizes, int n_in,
                              void* d_out, int out_size, void* d_ws, size_t ws_size,
                              hipStream_t stream) {
  const float* src  = (const float*)d_in[0];
  const float* tgt  = (const float*)d_in[1];
  const float* mask = (const float*)d_in[2];
  const float* W1   = (const float*)d_in[3];
  const float* b1   = (const float*)d_in[4];
  const float* w2   = (const float*)d_in[5];

  short* Bpk = (short*)d_ws;   // 512*1024 bf16 = 1 MB
  float* out = (float*)d_out;

  hipLaunchKernelGGL(prep_w1, dim3((K_ * D_) / 256), dim3(256), 0, stream, W1, Bpk);
  hipLaunchKernelGGL(fused_kernel, dim3(NBQ), dim3(NTHREADS), 0, stream,
                     src, tgt, mask, Bpk, b1, w2, out);
}